// Round 7
// baseline (8563.316 us; speedup 1.0000x reference)
//
#include <hip/hip_runtime.h>
#include <cstdint>
#include <cstddef>

// ---------------------------------------------------------------------------
// QLSTM: LSTM scan (recurrence) + batch-axis attention quirk, all-f16 internal.
// Pipeline: prep -> cvt_x -> GEMM xproj (frag-packed out) ->
//           MFMA scan (4 WGs x 16 batches, one barrier/step) ->
//           GEMM qkv -> fused per-(s,h) attention -> GEMM out_proj (+Hseq add)
// ws map (bytes):
//   [0, 134217728)          Xp f16 frag-packed [1024 t][4 g][64 nt][64 lane][4]
//                           (later reused: qkv at 0, ctx at 100663296)
//   [134217728, +33554432)  Xh f16 [65536][256]
//   [167772160, +33554432)  Hseq_h f16 [65536][256]
//   [201326592, +524288)    Bscan frag-major f16 (N=1024,K=256) — hx rows of W
//   [201850880, +524288)    Wxt frag-major f16 (N=1024,K=256)
//   [202375168, +393216)    in_proj frag-major f16 (N=768,K=256)
//   [202768384, +131072)    out_proj frag-major f16 (N=256,K=256)
//   [202899456, +4096)      bias4 f32 [1024]
//
// R7 = R6 resubmitted (container-acquisition failure, not a kernel verdict;
// barrier uniformity / buffer race / bounds / alignment re-audited clean).
//  R6 rationale: fdot2 scan plateaued at 2140us (allocator hard-caps arch
//  VGPRs by block size: 512->128, 1024->64; 192-pair weight array can never
//  be architectural; per-SIMD step = 2390 VALU + ~2600 stall vs 1024
//  essential). New: per step, gates[16b][1024n] = hx[16][256] @ Wh via mfma
//  16x16x32 (M=16 fully used). 4 WGs x 512thr (8 waves; wave w owns ntiles
//  w+8q). B streams from L2 each step (512KB, frag-major dwordx4) — no
//  register residency problem. A (hx) in 16KB double-buffered LDS frag buf.
//  Gate quads (f,i,g,o) of a column land in acc[q],acc[q+2],acc[q+4],acc[q+6]
//  of the SAME thread -> update needs no LDS exchange; ONE barrier/step.
//  xproj GEMM writes Xp pre-packed in C-frag order (EPI=2) so scan loads
//  xp as one dwordx2 per q, prefetched one step ahead.
// ---------------------------------------------------------------------------

typedef _Float16 f16;
typedef __attribute__((ext_vector_type(2))) _Float16 half2v;
typedef __attribute__((ext_vector_type(4))) _Float16 half4v;
typedef __attribute__((ext_vector_type(8))) _Float16 half8v;
typedef __attribute__((ext_vector_type(4))) float   float4v;

static __device__ __forceinline__ half2v u2h(unsigned u) {
  union { unsigned u; half2v h; } x; x.u = u; return x.h;
}
static __device__ __forceinline__ float rcp_fast(float x) {
  return __builtin_amdgcn_rcpf(x);
}
static __device__ __forceinline__ float sigm(float x) {
  return rcp_fast(1.0f + __expf(-x));
}
static __device__ __forceinline__ float tanh_fast(float x) {
  x = fminf(15.0f, fmaxf(-15.0f, x));
  float e = __expf(2.0f * x);
  return (e - 1.0f) * rcp_fast(e + 1.0f);
}
static __device__ __forceinline__ const float* selW(int g, const float* a, const float* b,
                                                    const float* c, const float* d) {
  return g == 0 ? a : (g == 1 ? b : (g == 2 ? c : d));
}

// LDS-only workgroup barrier: does NOT drain vmcnt, so global loads/stores
// (Xp prefetch, dout/Hh output) stay in flight across it.
static __device__ __forceinline__ void wg_barrier_lds() {
  __builtin_amdgcn_sched_barrier(0);
  asm volatile("s_waitcnt lgkmcnt(0)" ::: "memory");
  __builtin_amdgcn_s_barrier();
  __builtin_amdgcn_sched_barrier(0);
}

// ---------------------------------------------------------------------------
// prep: build f16 weight layouts.
//  seg0: Bscan frag-major (N=1024,K=256): value = W_g[(256+k)*256 + jj]
//  seg1: Wxt frag-major (N=1024,K=256):   value = W_g[k*256 + jj]
//  seg2: in_proj frag-major (N=768)
//  seg3: out_proj frag-major (N=256)
//  seg4: bias4[c] = b_g[j]
// frag-major B layout: flat = ((ntile*8 + kstep)*64 + lane)*8 + j ;
//   n = ntile*16 + (lane&15); k = kstep*32 + ((lane>>4)&3)*8 + j
// ---------------------------------------------------------------------------
__global__ void prep_k(const float* __restrict__ Wf, const float* __restrict__ Wi,
                       const float* __restrict__ Wg_, const float* __restrict__ Wo,
                       const float* __restrict__ bf, const float* __restrict__ bi,
                       const float* __restrict__ bg_, const float* __restrict__ bo,
                       const float* __restrict__ inpw, const float* __restrict__ outpw,
                       f16* __restrict__ wscan, f16* __restrict__ wxt,
                       f16* __restrict__ inpj, f16* __restrict__ outpj,
                       float* __restrict__ bias4)
{
  const int total = 262144 + 262144 + 196608 + 65536 + 1024;
  for (int e = blockIdx.x * blockDim.x + threadIdx.x; e < total; e += gridDim.x * blockDim.x) {
    int x = e;
    if (x < 262144) {                 // Bscan frag-major (hx rows 256..511)
      int j = x & 7, lane = (x >> 3) & 63, kstep = (x >> 9) & 7, ntile = x >> 12;
      int n = ntile * 16 + (lane & 15);
      int k = kstep * 32 + ((lane >> 4) & 3) * 8 + j;
      int g = n >> 8, jj = n & 255;
      const float* W = selW(g, Wf, Wi, Wg_, Wo);
      wscan[x] = (f16)W[(256 + k) * 256 + jj];
      continue;
    }
    x -= 262144;
    if (x < 262144) {                 // Wxt frag-major (N=1024)
      int j = x & 7, lane = (x >> 3) & 63, kstep = (x >> 9) & 7, ntile = x >> 12;
      int n = ntile * 16 + (lane & 15);
      int k = kstep * 32 + ((lane >> 4) & 3) * 8 + j;
      int g = n >> 8, jj = n & 255;
      const float* W = selW(g, Wf, Wi, Wg_, Wo);
      wxt[x] = (f16)W[k * 256 + jj];
      continue;
    }
    x -= 262144;
    if (x < 196608) {                 // in_proj frag-major (N=768)
      int j = x & 7, lane = (x >> 3) & 63, kstep = (x >> 9) & 7, ntile = x >> 12;
      int n = ntile * 16 + (lane & 15);
      int k = kstep * 32 + ((lane >> 4) & 3) * 8 + j;
      inpj[x] = (f16)inpw[k * 768 + n];
      continue;
    }
    x -= 196608;
    if (x < 65536) {                  // out_proj frag-major (N=256)
      int j = x & 7, lane = (x >> 3) & 63, kstep = (x >> 9) & 7, ntile = x >> 12;
      int n = ntile * 16 + (lane & 15);
      int k = kstep * 32 + ((lane >> 4) & 3) * 8 + j;
      outpj[x] = (f16)outpw[k * 256 + n];
      continue;
    }
    x -= 65536;
    {                                 // bias4
      int g = x >> 8, j = x & 255;
      const float* bp = selW(g, bf, bi, bg_, bo);
      bias4[x] = bp[j];
    }
  }
}

// ---------------------------------------------------------------------------
__global__ void cvt_x_k(const float4v* __restrict__ X, half4v* __restrict__ Xh)
{
  int i = blockIdx.x * 256 + threadIdx.x;   // grid sized exactly: 16777216/4
  float4v v = X[i];
  half4v h;
  h.x = (f16)v.x; h.y = (f16)v.y; h.z = (f16)v.z; h.w = (f16)v.w;
  Xh[i] = h;
}

// ---------------------------------------------------------------------------
// Generic MFMA GEMM: C[65536][NTOT] = A[65536][256](f16) @ Bfrag(N=NTOT,K=256)
// + bias[n].
//  EPI=0: store f16 row-major to Oh.
//  EPI=1: Of += f32 (row-major).
//  EPI=2: store f16 packed in scan C-frag order (NTOT must be 1024):
//         addr_f16(t,b,n) = t*65536 + (b>>4)*16384 + (n>>4)*256
//                           + (((b&15)>>2)*16 + (n&15))*4 + (b&3)
//         -> the epilogue's 4 r-values (4 consecutive rows = 4 consecutive b,
//            same t) pack into one 8B store.
// Block 256 thr (4 waves, 2x2 wave grid), tile 128x128, K chunks of 64.
// MFMA conventions (verified): A-frag lane holds A[m=lane&15][k=(lane>>4)*8+j];
// B-frag holds Bt[n=lane&15][k=...]; C/D: n=lane&15, m=(lane>>4)*4+reg.
// ---------------------------------------------------------------------------
template<int NTOT, int EPI>
__global__ __launch_bounds__(256, 2) void gemm_k(const f16* __restrict__ A,
    const f16* __restrict__ Bf, const float* __restrict__ bias,
    f16* __restrict__ Oh, float* __restrict__ Of)
{
  __shared__ f16 Al[8192];            // [8 mtiles][2 ksteps][64 lanes][8]
  const int tid = threadIdx.x;
  const int lane = tid & 63;
  const int wm = (tid >> 7) & 1;
  const int wn = (tid >> 6) & 1;
  const int m0 = blockIdx.y * 128, n0 = blockIdx.x * 128;

  float4v acc[4][4];
  #pragma unroll
  for (int i = 0; i < 4; ++i)
    #pragma unroll
    for (int j = 0; j < 4; ++j) { acc[i][j].x = 0.f; acc[i][j].y = 0.f; acc[i][j].z = 0.f; acc[i][j].w = 0.f; }

  #pragma unroll 1
  for (int kc = 0; kc < 4; ++kc) {
    __syncthreads();
    #pragma unroll
    for (int p = 0; p < 4; ++p) {
      int m = p * 32 + (tid >> 3);
      int kk = (tid & 7) * 8;
      half8v v = *(const half8v*)(A + (size_t)(m0 + m) * 256 + kc * 64 + kk);
      int lt = ((kk >> 3) & 3) * 16 + (m & 15);
      *(half8v*)(Al + (((m >> 4) * 2 + (kk >> 5)) * 64 + lt) * 8) = v;
    }
    __syncthreads();
    half8v bfr[4][2], afr[4][2];
    #pragma unroll
    for (int i = 0; i < 4; ++i) {
      int NT = (n0 >> 4) + wn * 4 + i;
      #pragma unroll
      for (int ks = 0; ks < 2; ++ks)
        bfr[i][ks] = *(const half8v*)(Bf + (size_t)((NT * 8 + kc * 2 + ks) * 64 + lane) * 8);
    }
    #pragma unroll
    for (int i = 0; i < 4; ++i) {
      int MT = wm * 4 + i;
      #pragma unroll
      for (int ks = 0; ks < 2; ++ks)
        afr[i][ks] = *(const half8v*)(Al + ((MT * 2 + ks) * 64 + lane) * 8);
    }
    #pragma unroll
    for (int ks = 0; ks < 2; ++ks)
      #pragma unroll
      for (int i = 0; i < 4; ++i)
        #pragma unroll
        for (int jn = 0; jn < 4; ++jn)
          acc[i][jn] = __builtin_amdgcn_mfma_f32_16x16x32_f16(afr[i][ks], bfr[jn][ks], acc[i][jn], 0, 0, 0);
  }

  const int r0 = (lane >> 4) * 4, cn = lane & 15;
  #pragma unroll
  for (int i = 0; i < 4; ++i) {
    #pragma unroll
    for (int jn = 0; jn < 4; ++jn) {
      int n = n0 + wn * 64 + jn * 16 + cn;
      float bv = bias[n];
      int mb = m0 + wm * 64 + i * 16 + r0;
      if constexpr (EPI == 2) {
        int t = mb >> 6, b = mb & 63;
        int gg = b >> 4, ms = b & 15;               // ms % 4 == 0
        half4v pk;
        #pragma unroll
        for (int r = 0; r < 4; ++r) pk[r] = (f16)(acc[i][jn][r] + bv);
        f16* dst = Oh + (size_t)t * 65536 + (size_t)gg * 16384
                      + (size_t)(n >> 4) * 256 + ((ms >> 2) * 16 + (n & 15)) * 4;
        *(half4v*)dst = pk;
      } else {
        #pragma unroll
        for (int r = 0; r < 4; ++r) {
          float v = acc[i][jn][r] + bv;
          size_t off = (size_t)(mb + r) * NTOT + n;
          if constexpr (EPI == 1) Of[off] = v + Of[off];
          else                    Oh[off] = (f16)v;
        }
      }
    }
  }
}

// ---------------------------------------------------------------------------
// MFMA LSTM scan. 4 WGs x 512 threads (8 waves); WG g owns batches g*16..+15.
// Per step: gates[16 m][1024 n] = hx[16][256] @ Wh  via mfma 16x16x32 (M=16
// fully used). Wave w computes ntiles nt = w + 8q, q=0..7 -> the (f,i,g,o) of
// hx column jj=(w+8q)*16+nl (q<2) live in acc[q],acc[q+2],acc[q+4],acc[q+6]
// of the SAME lane/register -> update is exchange-free.
//   A (hx): LDS [2 buf][8 ks][64 lane][8 f16] (16 KB), double-buffered; the
//           update writes hx(t+1) directly in A-frag layout. ONE barrier/step.
//   B (Wh): streamed frag-major from global every step (512 KB, L2-resident).
//   xp:     frag-packed by xproj GEMM (EPI=2); one dwordx2 per q, prefetched
//           one step ahead.
// Outputs: dout (Hseq f32) + Hh (f16) stores stay in flight (LDS-only barrier);
//          hx/cx tails written after the loop.
// ---------------------------------------------------------------------------
__global__ __launch_bounds__(512) void scan_k(const f16* __restrict__ Xpf,
    const f16* __restrict__ Bfrag, float* __restrict__ dout, f16* __restrict__ Hh)
{
  __shared__ f16 Al[2][8][64][8];              // 16 KB
  const int tid  = threadIdx.x;
  const int w    = tid >> 6;                   // wave 0..7
  const int lane = tid & 63;
  const int g    = blockIdx.x;                 // batch group 0..3

  // zero both A buffers (hx(0) = 0)
  {
    half8v z = {};
    for (int e = tid; e < 1024; e += 512) ((half8v*)Al)[e] = z;
  }

  float4v acc[8];
  float cx[2][4], hvk[2][4];
  #pragma unroll
  for (int q = 0; q < 2; ++q)
    #pragma unroll
    for (int r = 0; r < 4; ++r) { cx[q][r] = 0.0f; hvk[q][r] = 0.0f; }

  // xp frag address: f16 idx = t*65536 + g*16384 + (w+8q)*256 + lane*4
  const f16* xb = Xpf + (size_t)g * 16384 + (size_t)w * 256 + (size_t)lane * 4;
  uint2 xq[8];
  #pragma unroll
  for (int q = 0; q < 8; ++q) xq[q] = *(const uint2*)(xb + q * 2048);

  // B frag base for this wave: f16 idx = (w+8q)*4096 + ks*512 + lane*8
  const f16* bb = Bfrag + (size_t)w * 4096 + (size_t)lane * 8;

  __syncthreads();

  int cur = 0;
  #pragma unroll 1
  for (int t = 0; t < 1024; ++t) {
    // zero accumulators
    #pragma unroll
    for (int q = 0; q < 8; ++q) { acc[q].x = 0.f; acc[q].y = 0.f; acc[q].z = 0.f; acc[q].w = 0.f; }

    // prefetch next step's xp (L3-resident; arrives under the MFMA phase)
    uint2 xqn[8];
    if (t + 1 < 1024) {
      const f16* xn = xb + (size_t)(t + 1) * 65536;
      #pragma unroll
      for (int q = 0; q < 8; ++q) xqn[q] = *(const uint2*)(xn + q * 2048);
    } else {
      #pragma unroll
      for (int q = 0; q < 8; ++q) { xqn[q].x = 0u; xqn[q].y = 0u; }
    }

    // A frags for all 8 k-steps (LDS, 32 regs)
    half8v avp[8];
    #pragma unroll
    for (int ks = 0; ks < 8; ++ks)
      avp[ks] = *(const half8v*)&Al[cur][ks][lane][0];

    // MFMA phase: 64 MFMAs; B streamed from L2 (frag-major, dwordx4 each)
    #pragma unroll
    for (int ks = 0; ks < 8; ++ks) {
      #pragma unroll
      for (int q = 0; q < 8; ++q) {
        half8v bv = *(const half8v*)(bb + (size_t)q * 32768 + ks * 512);
        acc[q] = __builtin_amdgcn_mfma_f32_16x16x32_f16(avp[ks], bv, acc[q], 0, 0, 0);
      }
    }

    // update phase: exchange-free gate combine; writes hx(t+1) into Al[nxt]
    const int nxt = cur ^ 1;
    #pragma unroll
    for (int q = 0; q < 2; ++q) {
      const half2v xf_lo = u2h(xq[q].x),     xf_hi = u2h(xq[q].y);
      const half2v xi_lo = u2h(xq[q + 2].x), xi_hi = u2h(xq[q + 2].y);
      const half2v xg_lo = u2h(xq[q + 4].x), xg_hi = u2h(xq[q + 4].y);
      const half2v xo_lo = u2h(xq[q + 6].x), xo_hi = u2h(xq[q + 6].y);
      #pragma unroll
      for (int r = 0; r < 4; ++r) {
        float xf = (float)(r < 2 ? xf_lo[r & 1] : xf_hi[r & 1]);
        float xi = (float)(r < 2 ? xi_lo[r & 1] : xi_hi[r & 1]);
        float xg = (float)(r < 2 ? xg_lo[r & 1] : xg_hi[r & 1]);
        float xo = (float)(r < 2 ? xo_lo[r & 1] : xo_hi[r & 1]);
        float fv = sigm(acc[q][r] + xf);
        float iv = sigm(acc[q + 2][r] + xi);
        float gv = tanh_fast(acc[q + 4][r] + xg);
        float ov = sigm(acc[q + 6][r] + xo);
        float c  = fv * cx[q][r] + iv * gv;
        cx[q][r] = c;
        float hv = ov * tanh_fast(c);
        hvk[q][r] = hv;
        const int m  = ((lane >> 4) << 2) + r;           // batch-in-group 0..15
        const int jj = (w + 8 * q) * 16 + (lane & 15);   // hx column 0..255
        Al[nxt][jj >> 5][(((jj >> 3) & 3) << 4) + m][jj & 7] = (f16)hv;
        size_t off = (size_t)(t * 64 + g * 16 + m) * 256 + jj;
        dout[off] = hv;                                  // stores stay in flight
        Hh[off]   = (f16)hv;
      }
    }

    wg_barrier_lds();                                    // hx(t+1) visible
    cur = nxt;
    #pragma unroll
    for (int q = 0; q < 8; ++q) xq[q] = xqn[q];
  }

  // hx / cx tails
  #pragma unroll
  for (int q = 0; q < 2; ++q) {
    #pragma unroll
    for (int r = 0; r < 4; ++r) {
      const int m  = ((lane >> 4) << 2) + r;
      const int jj = (w + 8 * q) * 16 + (lane & 15);
      const int b  = g * 16 + m;
      dout[(size_t)16777216 + (size_t)b * 256 + jj]         = hvk[q][r];
      dout[(size_t)16777216 + 16384 + (size_t)b * 256 + jj] = cx[q][r];
    }
  }
}

// ---------------------------------------------------------------------------
// Fused batch-axis attention, one WG per (s, head). scores = q.k^T/8 over the
// B=64 axis, softmax, ctx = attn.v. f16 dot2, f32 accum, unnormalized-P trick.
// ---------------------------------------------------------------------------
__global__ __launch_bounds__(256, 2) void attn_k(const f16* __restrict__ qkv,
                                                 f16* __restrict__ ctx)
{
  __shared__ f16 ql[64 * 72];
  __shared__ f16 kl[64 * 72];
  __shared__ f16 vT[64 * 72];     // transposed: [d][k_b]
  __shared__ f16 at[64 * 72];     // exp'd scores (unnormalized), [q_b][k_b]
  __shared__ float sc[64 * 69];
  __shared__ float pmx[256], psm[256], rmx[64], rsm[64];
  const int tid = threadIdx.x;
  const int s = blockIdx.x >> 2, h = blockIdx.x & 3;
  {
    const int bb = tid >> 2, i = tid & 3;
    const f16* base = qkv + (size_t)(s * 64 + bb) * 768 + h * 64 + i * 16;
    half8v q0 = *(const half8v*)(base);
    half8v q1 = *(const half8v*)(base + 8);
    *(half8v*)(ql + bb * 72 + i * 16)     = q0;
    *(half8v*)(ql + bb * 72 + i * 16 + 8) = q1;
    half8v k0 = *(const half8v*)(base + 256);
    half8v k1 = *(const half8v*)(base + 264);
    *(half8v*)(kl + bb * 72 + i * 16)     = k0;
    *(half8v*)(kl + bb * 72 + i * 16 + 8) = k1;
    half8v v0 = *(const half8v*)(base + 512);
    half8v v1 = *(const half8v*)(base + 520);
    #pragma unroll
    for (int z = 0; z < 8; ++z) {
      vT[(i * 16 + z) * 72 + bb]     = v0[z];
      vT[(i * 16 + 8 + z) * 72 + bb] = v1[z];
    }
  }
  __syncthreads();
  {
    const int qb = tid >> 2, g = tid & 3;
    half8v qr[8];
    #pragma unroll
    for (int i = 0; i < 8; ++i) qr[i] = *(const half8v*)(ql + qb * 72 + i * 8);
    #pragma unroll 1
    for (int jj = 0; jj < 16; ++jj) {
      int kb = g + jj * 4;
      float a = 0.0f;
      #pragma unroll
      for (int i = 0; i < 8; ++i) {
        half8v kr = *(const half8v*)(kl + kb * 72 + i * 8);
        const half2v* kp = (const half2v*)&kr;
        const half2v* qp = (const half2v*)&qr[i];
        #pragma unroll
        for (int z = 0; z < 4; ++z) a = __builtin_amdgcn_fdot2(qp[z], kp[z], a, false);
      }
      sc[qb * 69 + kb] = a * 0.125f;
    }
  }
  __syncthreads();
  {
    const int r = tid & 63, q = tid >> 6;
    float m = -1e30f;
    #pragma unroll
    for (int z = 0; z < 16; ++z) m = fmaxf(m, sc[r * 69 + q * 16 + z]);
    pmx[q * 64 + r] = m;
  }
  __syncthreads();
  if (tid < 64)
    rmx[tid] = fmaxf(fmaxf(pmx[tid], pmx[64 + tid]), fmaxf(pmx[128 + tid], pmx[192 + tid]));
  __syncthreads();
  {
    const int r = tid & 63, q = tid >> 6;
    float mx = rmx[r], ssum = 0.0f;
    #pragma unroll
    for (int z = 0; z < 16; ++z) {
      float e = __expf(sc[r * 69 + q * 16 + z] - mx);
      ssum += e;
      at[r * 72 + q * 16 + z] = (f16)e;
    }
    psm[q * 64 + r] = ssum;
  }
  __syncthreads();
  if (tid < 64)
    rsm[tid] = (psm[tid] + psm[64 + tid]) + (psm[128 + tid] + psm[192 + tid]);
  __syncthreads();
  {
    const int qb = tid >> 2, g = tid & 3;
    half8v ar[8];
    #pragma unroll
    for (int i = 0; i < 8; ++i) ar[i] = *(const half8v*)(at + qb * 72 + i * 8);
    const float rinv = 1.0f / rsm[qb];
    f16* outp = ctx + (size_t)(s * 64 + qb) * 256 + h * 64;
    #pragma unroll 1
    for (int z = 0; z < 16; ++z) {
      int d = g + z * 4;
      float a = 0.0f;
      #pragma unroll
      for (int i = 0; i < 8; ++i) {
        half8v vr = *(const half8v*)(vT + d * 72 + i * 8);
        const half2v* vp = (const half2v*)&vr;
        const half2v* ap = (const half2v*)&ar[i];
        #pragma unroll
        for (int zz = 0; zz < 4; ++zz) a = __builtin_amdgcn_fdot2(ap[zz], vp[zz], a, false);
      }
      outp[d] = (f16)(a * rinv);
    }
  }
}

// ---------------------------------------------------------------------------
extern "C" void kernel_launch(void* const* d_in, const int* in_sizes, int n_in,
                              void* d_out, int out_size, void* d_ws, size_t ws_size,
                              hipStream_t stream)
{
  (void)in_sizes; (void)n_in; (void)out_size; (void)ws_size;
  const float* X    = (const float*)d_in[0];
  const float* Wf   = (const float*)d_in[1];
  const float* bf   = (const float*)d_in[2];
  const float* Wi   = (const float*)d_in[3];
  const float* bi   = (const float*)d_in[4];
  const float* Wg   = (const float*)d_in[5];
  const float* bg   = (const float*)d_in[6];
  const float* Wo   = (const float*)d_in[7];
  const float* bo   = (const float*)d_in[8];
  const float* inpw = (const float*)d_in[9];
  const float* inpb = (const float*)d_in[10];
  const float* outpw= (const float*)d_in[11];
  const float* outpb= (const float*)d_in[12];

  char* ws = (char*)d_ws;
  f16*   Xp    = (f16*)(ws + 0);
  f16*   qkv   = (f16*)(ws + 0);                 // reuses Xp region after scan
  f16*   ctxh  = (f16*)(ws + 100663296);         // also inside old Xp region
  f16*   Xh    = (f16*)(ws + 134217728);
  f16*   Hh    = (f16*)(ws + 167772160);
  f16*   wscan = (f16*)(ws + 201326592);
  f16*   wxt   = (f16*)(ws + 201850880);
  f16*   inpj  = (f16*)(ws + 202375168);
  f16*   outpj = (f16*)(ws + 202768384);
  float* bias4 = (float*)(ws + 202899456);
  float* out   = (float*)d_out;

  prep_k<<<1024, 256, 0, stream>>>(Wf, Wi, Wg, Wo, bf, bi, bg, bo, inpw, outpw,
                                   wscan, wxt, inpj, outpj, bias4);
  cvt_x_k<<<16384, 256, 0, stream>>>((const float4v*)X, (half4v*)Xh);
  gemm_k<1024, 2><<<dim3(8, 512), 256, 0, stream>>>(Xh, wxt, bias4, Xp, nullptr);
  scan_k<<<4, 512, 0, stream>>>(Xp, wscan, out, Hh);
  gemm_k<768, 0><<<dim3(6, 512), 256, 0, stream>>>(Hh, inpj, inpb, qkv, nullptr);
  attn_k<<<4096, 256, 0, stream>>>(qkv, ctxh);
  gemm_k<256, 1><<<dim3(2, 512), 256, 0, stream>>>(ctxh, outpj, outpb, nullptr, out);
}